// Round 10
// baseline (1538.489 us; speedup 1.0000x reference)
//
#include <hip/hip_runtime.h>
#include <hip/hip_cooperative_groups.h>

namespace cg = cooperative_groups;

#define N_TOK 8192
#define DIM   1024
#define FFN   4096
#define NEXP  8
#define TOPK  2
#define NENT  (N_TOK * TOPK)   // 16384
#define MAXM  20               // max 128-row m-tiles per expert

using short8   = __attribute__((ext_vector_type(8))) short;
using ushort8v = __attribute__((ext_vector_type(8))) unsigned short;
using floatx4  = __attribute__((ext_vector_type(4))) float;

__device__ __forceinline__ unsigned short f2bf(float f) {
    union { float f; unsigned u; } v; v.f = f;
    unsigned r = v.u + 0x7fffu + ((v.u >> 16) & 1u);   // round-to-nearest-even
    return (unsigned short)(r >> 16);
}

#define GLOAD_LDS16(gptr, lptr) __builtin_amdgcn_global_load_lds( \
    (__attribute__((address_space(1))) void*)(void*)(gptr),       \
    (__attribute__((address_space(3))) void*)(lptr), 16, 0, 0)

struct MoeArgs {
    const float* x; const float* Wg; const float* W1; const float* b1;
    const float* W2; const float* b2;
    unsigned short* xb; unsigned short* w1t; unsigned short* w2t; unsigned short* h;
    int* topk_e; float* topk_w; int* entry_token; float* entry_w;
    int* counters;   // [0:8) counts, [8:16) cursors, [16:24) qC, [24:32) qD
    float* y;
};

union __align__(16) Smem {
    struct { unsigned short As[2][4096]; unsigned short Bs[2][4096]; int toks[128]; } g;
    float tile[8192];   // 32 KB f32 transpose tile
};

// ---------------- f32->bf16 transpose tile: 256 rows x 32 cols ----------------
// float4 loads (8 in flight/thread), LDS 16B-chunk XOR swizzle, ushort8 stores.

__device__ __forceinline__ void transpose_tile(const float* __restrict__ inp,
                                               unsigned short* __restrict__ outp,
                                               int R, int C, int r0, int c0,
                                               float* tile) {
    int t = threadIdx.x;
    int p = t & 7;
    int trow = t >> 3;
    int w = t >> 6;
#pragma unroll
    for (int i = 0; i < 8; i++) {
        int r = i * 32 + trow;
        float4 v = *(const float4*)&inp[(size_t)(r0 + r) * C + c0 + p * 4];
        int cc = p ^ ((4 * i + w) & 7);
        *(float4*)&tile[r * 32 + cc * 4] = v;
    }
    __syncthreads();
    int c = t >> 3;
    int cbase = ((c >> 2) ^ p) * 4 + (c & 3);
    unsigned short* orow = outp + (size_t)(c0 + c) * R + r0;
#pragma unroll
    for (int j = 0; j < 4; j++) {
        int rb = j * 64 + p * 8;
        ushort8v us;
#pragma unroll
        for (int k = 0; k < 8; k++)
            us[k] = f2bf(tile[(rb + k) * 32 + cbase]);
        *(ushort8v*)&orow[rb] = us;
    }
}

// ---------------- gating job: 4 tokens (1/wave), x->bf16 fused ----------------

__device__ void gating_job(const MoeArgs& a, int gj) {
    int tid = threadIdx.x;
    int wave = tid >> 6, lane = tid & 63;
    int t = gj * 4 + wave;
    const float* xr = a.x + (size_t)t * DIM;
    unsigned short* xbr = a.xb + (size_t)t * DIM;
    float acc[NEXP];
#pragma unroll
    for (int e = 0; e < NEXP; e++) acc[e] = 0.f;
    for (int it = 0; it < DIM / 256; it++) {
        int d = it * 256 + lane * 4;
        float4 xv = *(const float4*)&xr[d];
        ushort4 ub;
        ub.x = f2bf(xv.x); ub.y = f2bf(xv.y); ub.z = f2bf(xv.z); ub.w = f2bf(xv.w);
        *(ushort4*)&xbr[d] = ub;
        const float* wp = a.Wg + (size_t)d * NEXP;
#pragma unroll
        for (int j = 0; j < 4; j++) {
            float xj = (j == 0) ? xv.x : (j == 1) ? xv.y : (j == 2) ? xv.z : xv.w;
            const float4* wr = (const float4*)(wp + j * NEXP);
            float4 w0 = wr[0], w1 = wr[1];
            acc[0] += xj * w0.x; acc[1] += xj * w0.y; acc[2] += xj * w0.z; acc[3] += xj * w0.w;
            acc[4] += xj * w1.x; acc[5] += xj * w1.y; acc[6] += xj * w1.z; acc[7] += xj * w1.w;
        }
    }
#pragma unroll
    for (int e = 0; e < NEXP; e++) {
#pragma unroll
        for (int off = 32; off > 0; off >>= 1) acc[e] += __shfl_xor(acc[e], off);
    }
    if (lane == 0) {
        int e1 = 0; float l1 = acc[0];
        for (int e = 1; e < NEXP; e++) if (acc[e] > l1) { l1 = acc[e]; e1 = e; }
        int e2 = -1; float l2 = -3.4e38f;
        for (int e = 0; e < NEXP; e++) if (e != e1 && acc[e] > l2) { l2 = acc[e]; e2 = e; }
        float w1v = 1.f / (1.f + expf(l2 - l1));
        a.topk_e[t * 2]     = e1;  a.topk_e[t * 2 + 1] = e2;
        a.topk_w[t * 2]     = w1v; a.topk_w[t * 2 + 1] = 1.f - w1v;
        atomicAdd(&a.counters[e1], 1);
        atomicAdd(&a.counters[e2], 1);
    }
}

// ---------------- GEMM1 job: h = relu(x[tok] @ W1_e + b1_e), 128x128, BK=32 ----------------

__device__ void gemm1_job(const MoeArgs& a, Smem& sm, int bid) {
    int xcd   = bid & 7;
    int inner = bid >> 3;
    int gq    = inner / MAXM;
    int mt    = inner - gq * MAXM;
    int g     = gq * 8 + xcd;             // group 0..255
    int e     = g >> 5;
    int nt    = g & 31;
    int base = 0;
    for (int i = 0; i < e; i++) base += a.counters[i];
    int cnt = a.counters[e];
    int m0  = mt * 128;
    if (m0 >= cnt) return;
    int f0  = nt * 128;

    auto& As   = sm.g.As;
    auto& Bs   = sm.g.Bs;
    auto& toks = sm.g.toks;

    int tid = threadIdx.x;
    if (tid < 128) {
        int r = m0 + tid;
        toks[tid] = a.entry_token[base + (r < cnt ? r : 0)];
    }
    __syncthreads();

    int wave = tid >> 6, lane = tid & 63;
    int wm = (wave >> 1) * 64, wn = (wave & 1) * 64;

    int lr = lane >> 2, sl = lane & 3;
    int g0 = (sl ^ ((lr >> 1) & 3)) * 8;
    const unsigned short* aG[2];
    const unsigned short* bG[2];
    int ldsOff[2];
#pragma unroll
    for (int c = 0; c < 2; c++) {
        int row = wave * 32 + c * 16 + lr;
        aG[c] = a.xb + (size_t)toks[row] * DIM + g0;
        bG[c] = a.w1t + ((size_t)e * FFN + f0 + row) * DIM + g0;
        ldsOff[c] = (wave * 32 + c * 16) * 32;
    }

    floatx4 acc[4][4];
#pragma unroll
    for (int i = 0; i < 4; i++)
#pragma unroll
        for (int j = 0; j < 4; j++) acc[i][j] = (floatx4)0.f;

    int quad = lane >> 4, rm = lane & 15;
    int slf  = (quad ^ ((rm >> 1) & 3)) * 8;
    int arow = (wm + rm) * 32;
    int brow = (wn + rm) * 32;

#pragma unroll
    for (int c = 0; c < 2; c++) {
        GLOAD_LDS16(aG[c], &As[0][ldsOff[c]]);
        GLOAD_LDS16(bG[c], &Bs[0][ldsOff[c]]);
        aG[c] += 32; bG[c] += 32;
    }

    int cur = 0;
    for (int kk = 0; kk < DIM / 32; kk++) {
        __syncthreads();
        short8 af[4], bfr[4];
#pragma unroll
        for (int mi = 0; mi < 4; mi++) af[mi] = *(const short8*)&As[cur][arow + mi * 512 + slf];
#pragma unroll
        for (int ni = 0; ni < 4; ni++) bfr[ni] = *(const short8*)&Bs[cur][brow + ni * 512 + slf];
        if (kk + 1 < DIM / 32) {
            int nxt = cur ^ 1;
#pragma unroll
            for (int c = 0; c < 2; c++) {
                GLOAD_LDS16(aG[c], &As[nxt][ldsOff[c]]);
                GLOAD_LDS16(bG[c], &Bs[nxt][ldsOff[c]]);
                aG[c] += 32; bG[c] += 32;
            }
        }
#pragma unroll
        for (int mi = 0; mi < 4; mi++)
#pragma unroll
            for (int ni = 0; ni < 4; ni++)
                acc[mi][ni] = __builtin_amdgcn_mfma_f32_16x16x32_bf16(af[mi], bfr[ni], acc[mi][ni], 0, 0, 0);
        cur ^= 1;
    }

#pragma unroll
    for (int mi = 0; mi < 4; mi++) {
        int mbase = wm + mi * 16 + quad * 4;
#pragma unroll
        for (int ni = 0; ni < 4; ni++) {
            int f = f0 + wn + ni * 16 + rm;
            float bias = a.b1[e * FFN + f];
            floatx4 v = acc[mi][ni];
#pragma unroll
            for (int r = 0; r < 4; r++) {
                int row = m0 + mbase + r;
                if (row < cnt) {
                    float t = v[r] + bias;
                    t = t > 0.f ? t : 0.f;
                    a.h[(size_t)(base + row) * FFN + f] = f2bf(t);
                }
            }
        }
    }
}

// ---------------- GEMM2 job + fused combine: y[tok] += w * (h @ W2_e + b2_e) ----------------

__device__ void gemm2_job(const MoeArgs& a, Smem& sm, int bid) {
    int e    = bid & 7;
    int grp  = bid % (8 * MAXM);
    int mt   = grp >> 3;               // m fast
    int nt   = bid / (8 * MAXM);       // 0..7 outer
    int base = 0;
    for (int i = 0; i < e; i++) base += a.counters[i];
    int cnt = a.counters[e];
    int m0  = mt * 128;
    if (m0 >= cnt) return;
    int n0  = nt * 128;

    auto& As = sm.g.As;
    auto& Bs = sm.g.Bs;

    int tid = threadIdx.x;
    int wave = tid >> 6, lane = tid & 63;
    int wm = (wave >> 1) * 64, wn = (wave & 1) * 64;

    int lr = lane >> 2, sl = lane & 3;
    int g0 = (sl ^ ((lr >> 1) & 3)) * 8;
    const unsigned short* aG[2];
    const unsigned short* bG[2];
    int ldsOff[2];
#pragma unroll
    for (int c = 0; c < 2; c++) {
        int row = wave * 32 + c * 16 + lr;
        aG[c] = a.h + (size_t)(base + m0 + row) * FFN + g0;
        bG[c] = a.w2t + ((size_t)e * DIM + n0 + row) * FFN + g0;
        ldsOff[c] = (wave * 32 + c * 16) * 32;
    }

    floatx4 acc[4][4];
#pragma unroll
    for (int i = 0; i < 4; i++)
#pragma unroll
        for (int j = 0; j < 4; j++) acc[i][j] = (floatx4)0.f;

    int quad = lane >> 4, rm = lane & 15;
    int slf  = (quad ^ ((rm >> 1) & 3)) * 8;
    int arow = (wm + rm) * 32;
    int brow = (wn + rm) * 32;

#pragma unroll
    for (int c = 0; c < 2; c++) {
        GLOAD_LDS16(aG[c], &As[0][ldsOff[c]]);
        GLOAD_LDS16(bG[c], &Bs[0][ldsOff[c]]);
        aG[c] += 32; bG[c] += 32;
    }

    int cur = 0;
    for (int kk = 0; kk < FFN / 32; kk++) {
        __syncthreads();
        short8 af[4], bfr[4];
#pragma unroll
        for (int mi = 0; mi < 4; mi++) af[mi] = *(const short8*)&As[cur][arow + mi * 512 + slf];
#pragma unroll
        for (int ni = 0; ni < 4; ni++) bfr[ni] = *(const short8*)&Bs[cur][brow + ni * 512 + slf];
        if (kk + 1 < FFN / 32) {
            int nxt = cur ^ 1;
#pragma unroll
            for (int c = 0; c < 2; c++) {
                GLOAD_LDS16(aG[c], &As[nxt][ldsOff[c]]);
                GLOAD_LDS16(bG[c], &Bs[nxt][ldsOff[c]]);
                aG[c] += 32; bG[c] += 32;
            }
        }
#pragma unroll
        for (int mi = 0; mi < 4; mi++)
#pragma unroll
            for (int ni = 0; ni < 4; ni++)
                acc[mi][ni] = __builtin_amdgcn_mfma_f32_16x16x32_bf16(af[mi], bfr[ni], acc[mi][ni], 0, 0, 0);
        cur ^= 1;
    }

    float bs[4];
#pragma unroll
    for (int ni = 0; ni < 4; ni++) bs[ni] = a.b2[e * DIM + n0 + wn + ni * 16 + rm];
#pragma unroll
    for (int mi = 0; mi < 4; mi++) {
        int mbase = wm + mi * 16 + quad * 4;
#pragma unroll
        for (int r = 0; r < 4; r++) {
            int row = m0 + mbase + r;
            if (row < cnt) {
                int tok = a.entry_token[base + row];
                float w = a.entry_w[base + row];
                float* yr = a.y + (size_t)tok * DIM;
#pragma unroll
                for (int ni = 0; ni < 4; ni++) {
                    int n = n0 + wn + ni * 16 + rm;
                    atomicAdd(&yr[n], w * (acc[mi][ni][r] + bs[ni]));
                }
            }
        }
    }
}

// ---------------- single cooperative kernel: 4 phases, grid.sync between ----------------
// Phase A: W1-T (4096) + W2-T (4096) + gating (2048), static stride — streaming
//   phase kept SEPARATE from GEMMs (r9: co-residency polluted L2, +93MB FETCH).
// Phase B: scatter (32) + y-zero (512).
// Phase C: gemm1, 5120 jobs via per-XCD atomic queues (job = inner*8 + blockIdx%8
//   == the proven static swizzle, plus dynamic balance within each XCD).
// Phase D: gemm2, 1280 jobs, same per-XCD queues (e = job&7 pinned per XCD).

__global__ __launch_bounds__(256, 3) void moe_kernel(MoeArgs a) {
    __shared__ Smem sm;
    __shared__ int nextJob;
    cg::grid_group grid = cg::this_grid();
    int nb = gridDim.x, bx = blockIdx.x, tid = threadIdx.x;
    int* qC = a.counters + 16;
    int* qD = a.counters + 24;

    // ---- Phase A ----
    for (int vb = bx; vb < 10240; vb += nb) {
        if (vb < 4096) {
            int rt = vb & 3, ct = (vb >> 2) & 127, e = vb >> 9;
            transpose_tile(a.W1 + (size_t)e * DIM * FFN, a.w1t + (size_t)e * DIM * FFN,
                           DIM, FFN, rt * 256, ct * 32, sm.tile);
            __syncthreads();
        } else if (vb < 8192) {
            int tb = vb - 4096;
            int rt = tb & 15, ct = (tb >> 4) & 31, e = tb >> 9;
            transpose_tile(a.W2 + (size_t)e * DIM * FFN, a.w2t + (size_t)e * DIM * FFN,
                           FFN, DIM, rt * 256, ct * 32, sm.tile);
            __syncthreads();
        } else {
            gating_job(a, vb - 8192);
        }
    }
    grid.sync();

    // ---- Phase B ----
    for (int vb = bx; vb < 544; vb += nb) {
        if (vb < 32) {
            int off_[NEXP]; int s = 0;
#pragma unroll
            for (int e = 0; e < NEXP; e++) { off_[e] = s; s += a.counters[e]; }
            int* cursors = a.counters + 8;
            int t = vb * 256 + tid;
#pragma unroll
            for (int k = 0; k < TOPK; k++) {
                int e = a.topk_e[t * 2 + k];
                int pos = off_[e] + atomicAdd(&cursors[e], 1);
                a.entry_token[pos] = t;
                a.entry_w[pos] = a.topk_w[t * 2 + k];
            }
        } else {
            float4 z = make_float4(0.f, 0.f, 0.f, 0.f);
            float4* yp = (float4*)a.y;
            size_t b0 = (size_t)(vb - 32) * 256 + tid;
#pragma unroll
            for (int i = 0; i < 16; i++)
                yp[b0 + (size_t)i * 512 * 256] = z;
        }
    }
    grid.sync();

    // ---- Phase C: gemm1 (5120 jobs, 640/XCD) ----
    int myq = bx & 7;
    for (;;) {
        if (tid == 0) nextJob = atomicAdd(&qC[myq], 1);
        __syncthreads();
        int inner = nextJob;
        if (inner >= 640) break;
        gemm1_job(a, sm, inner * 8 + myq);
        __syncthreads();
    }
    grid.sync();

    // ---- Phase D: gemm2 (1280 jobs, 160/XCD) ----
    for (;;) {
        if (tid == 0) nextJob = atomicAdd(&qD[myq], 1);
        __syncthreads();
        int inner = nextJob;
        if (inner >= 160) break;
        gemm2_job(a, sm, inner * 8 + myq);
        __syncthreads();
    }
}

// ---------------- launch ----------------

extern "C" void kernel_launch(void* const* d_in, const int* in_sizes, int n_in,
                              void* d_out, int out_size, void* d_ws, size_t ws_size,
                              hipStream_t stream) {
    const float* x  = (const float*)d_in[0];
    const float* Wg = (const float*)d_in[1];
    const float* W1 = (const float*)d_in[2];
    const float* b1 = (const float*)d_in[3];
    const float* W2 = (const float*)d_in[4];
    const float* b2 = (const float*)d_in[5];
    float* y = (float*)d_out;

    char* p = (char*)d_ws;
    unsigned short* xb  = (unsigned short*)p; p += (size_t)N_TOK * DIM * 2;          // 16 MB
    unsigned short* w1t = (unsigned short*)p; p += (size_t)NEXP * DIM * FFN * 2;     // 64 MB
    unsigned short* w2t = (unsigned short*)p; p += (size_t)NEXP * DIM * FFN * 2;     // 64 MB
    unsigned short* h   = (unsigned short*)p; p += (size_t)(NENT + 128) * FFN * 2;   // 129 MB
    int*   topk_e      = (int*)p;   p += (size_t)N_TOK * TOPK * 4;
    float* topk_w      = (float*)p; p += (size_t)N_TOK * TOPK * 4;
    int*   entry_token = (int*)p;   p += (size_t)NENT * 4;
    float* entry_w     = (float*)p; p += (size_t)NENT * 4;
    int*   counters    = (int*)p;   p += 32 * 4;   // counts8 | cursors8 | qC8 | qD8

    hipMemsetAsync(counters, 0, 32 * 4, stream);

    static int nblk = 0;
    if (nblk == 0) {
        int mb = 0;
        hipOccupancyMaxActiveBlocksPerMultiprocessor(&mb, moe_kernel, 256, 0);
        if (mb < 1) mb = 1;
        if (mb > 3) mb = 3;
        nblk = 256 * mb;
    }

    MoeArgs args;
    args.x = x; args.Wg = Wg; args.W1 = W1; args.b1 = b1; args.W2 = W2; args.b2 = b2;
    args.xb = xb; args.w1t = w1t; args.w2t = w2t; args.h = h;
    args.topk_e = topk_e; args.topk_w = topk_w;
    args.entry_token = entry_token; args.entry_w = entry_w;
    args.counters = counters; args.y = y;

    void* kp[] = { &args };
    hipLaunchCooperativeKernel(moe_kernel, dim3(nblk), dim3(256), kp, 0, stream);
}

// Round 15
// 990.076 us; speedup vs baseline: 1.5539x; 1.5539x over previous
//
#include <hip/hip_runtime.h>

#define N_TOK 8192
#define DIM   1024
#define FFN   4096
#define NEXP  8
#define TOPK  2
#define NENT  (N_TOK * TOPK)   // 16384
#define MAXM  20               // max 128-row m-tiles per expert

using short8   = __attribute__((ext_vector_type(8))) short;
using ushort8v = __attribute__((ext_vector_type(8))) unsigned short;
using floatx4  = __attribute__((ext_vector_type(4))) float;

__device__ __forceinline__ unsigned short f2bf(float f) {
    union { float f; unsigned u; } v; v.f = f;
    unsigned r = v.u + 0x7fffu + ((v.u >> 16) & 1u);   // round-to-nearest-even
    return (unsigned short)(r >> 16);
}

#define GLOAD_LDS16(gptr, lptr) __builtin_amdgcn_global_load_lds( \
    (__attribute__((address_space(1))) void*)(void*)(gptr),       \
    (__attribute__((address_space(3))) void*)(lptr), 16, 0, 0)

// ---------------- f32->bf16 transpose tile: 128 rows x 64 cols ----------------
// Both sides 256 B granules (reads: 64 cols x 4 B per row-visit; writes: 128
// rows x 2 B per out-row) — the old 256x32 tile read 128 B-sparse. LDS padded
// [128][68] f32: float4-aligned rows, (68 mod 32 = 4) shifts banks 1 quad/row.
// 8 independent float4 loads/thread; rt-fastest block order -> consecutive
// blocks write adjacent 256 B segments of the same output rows (dense streams).

__device__ __forceinline__ void transpose_tile(const float* __restrict__ inp,
                                               unsigned short* __restrict__ outp,
                                               int R, int C, int r0, int c0,
                                               float* __restrict__ tile) {
    int t = threadIdx.x;
    int p = t & 15, q = t >> 4;       // col-chunk, row subgroup
#pragma unroll
    for (int i = 0; i < 8; i++) {
        int r = i * 16 + q;
        float4 v = *(const float4*)&inp[(size_t)(r0 + r) * C + c0 + p * 4];
        *(float4*)&tile[r * 68 + p * 4] = v;
    }
    __syncthreads();
    int c = t >> 2, s = t & 3;        // out-row (input col), segment
    unsigned short* orow = outp + (size_t)(c0 + c) * R + r0;
#pragma unroll
    for (int j = 0; j < 4; j++) {
        int rb = j * 32 + s * 8;      // 4-lane groups cover 64 B contiguous
        ushort8v us;
#pragma unroll
        for (int k = 0; k < 8; k++)
            us[k] = f2bf(tile[(rb + k) * 68 + c]);
        *(ushort8v*)&orow[rb] = us;
    }
}

// ---------------- prep: W1 transpose (blocks 0..4095, rt-fastest) + gating ----------------

__global__ __launch_bounds__(256) void prep_kernel(
    const float* __restrict__ W1, unsigned short* __restrict__ w1t,
    const float* __restrict__ x, const float* __restrict__ wg,
    unsigned short* __restrict__ xb,
    int* __restrict__ topk_e, float* __restrict__ topk_w,
    int* __restrict__ counts)
{
    __shared__ float tile[128 * 68];   // 34 KB
    int bid = blockIdx.x;
    if (bid < 4096) {
        // W1: R=DIM=1024 (8 rt), C=FFN=4096 (64 ct)
        int rt = bid & 7;
        int ct = (bid >> 3) & 63;
        int e  = bid >> 9;
        transpose_tile(W1 + (size_t)e * DIM * FFN, w1t + (size_t)e * DIM * FFN,
                       DIM, FFN, rt * 128, ct * 64, tile);
        return;
    }

    // ---- gating (+ x -> bf16), 4 tokens/block ----
    int tid = threadIdx.x;
    int wave = tid >> 6, lane = tid & 63;
    int t = (bid - 4096) * 4 + wave;
    const float* xr = x + (size_t)t * DIM;
    unsigned short* xbr = xb + (size_t)t * DIM;
    float acc[NEXP];
#pragma unroll
    for (int e = 0; e < NEXP; e++) acc[e] = 0.f;
    for (int it = 0; it < DIM / 256; it++) {
        int d = it * 256 + lane * 4;
        float4 xv = *(const float4*)&xr[d];
        ushort4 ub;
        ub.x = f2bf(xv.x); ub.y = f2bf(xv.y); ub.z = f2bf(xv.z); ub.w = f2bf(xv.w);
        *(ushort4*)&xbr[d] = ub;
        const float* wp = wg + (size_t)d * NEXP;
#pragma unroll
        for (int j = 0; j < 4; j++) {
            float xj = (j == 0) ? xv.x : (j == 1) ? xv.y : (j == 2) ? xv.z : xv.w;
            const float4* wr = (const float4*)(wp + j * NEXP);
            float4 w0 = wr[0], w1 = wr[1];
            acc[0] += xj * w0.x; acc[1] += xj * w0.y; acc[2] += xj * w0.z; acc[3] += xj * w0.w;
            acc[4] += xj * w1.x; acc[5] += xj * w1.y; acc[6] += xj * w1.z; acc[7] += xj * w1.w;
        }
    }
#pragma unroll
    for (int e = 0; e < NEXP; e++) {
#pragma unroll
        for (int off = 32; off > 0; off >>= 1) acc[e] += __shfl_xor(acc[e], off);
    }
    if (lane == 0) {
        int e1 = 0; float l1 = acc[0];
        for (int e = 1; e < NEXP; e++) if (acc[e] > l1) { l1 = acc[e]; e1 = e; }
        int e2 = -1; float l2 = -3.4e38f;
        for (int e = 0; e < NEXP; e++) if (e != e1 && acc[e] > l2) { l2 = acc[e]; e2 = e; }
        float w1v = 1.f / (1.f + expf(l2 - l1));   // softmax top-2 renormalized
        topk_e[t * 2]     = e1;  topk_e[t * 2 + 1] = e2;
        topk_w[t * 2]     = w1v; topk_w[t * 2 + 1] = 1.f - w1v;
        atomicAdd(&counts[e1], 1);
        atomicAdd(&counts[e2], 1);
    }
}

// ---------------- scatter (prefix fused) + y zeroing ----------------

__global__ __launch_bounds__(256) void scatter_kernel(const int* __restrict__ topk_e,
                                                      const float* __restrict__ topk_w,
                                                      const int* __restrict__ counts,
                                                      int* __restrict__ offs,
                                                      int* __restrict__ cursors,
                                                      int* __restrict__ entry_token,
                                                      float* __restrict__ entry_w,
                                                      float* __restrict__ y) {
    if (blockIdx.x >= 32) {
        float4 z = make_float4(0.f, 0.f, 0.f, 0.f);
        float4* yp = (float4*)y;
        size_t base = (size_t)(blockIdx.x - 32) * 256 + threadIdx.x;
#pragma unroll
        for (int i = 0; i < 16; i++)
            yp[base + (size_t)i * 512 * 256] = z;
        return;
    }
    int off_[NEXP]; int s = 0;
#pragma unroll
    for (int e = 0; e < NEXP; e++) { off_[e] = s; s += counts[e]; }
    if (blockIdx.x == 0 && threadIdx.x == 0) {
#pragma unroll
        for (int e = 0; e < NEXP; e++) offs[e] = off_[e];
        offs[NEXP] = s;
    }
    int t = blockIdx.x * 256 + threadIdx.x;
#pragma unroll
    for (int k = 0; k < TOPK; k++) {
        int e = topk_e[t * 2 + k];
        int pos = off_[e] + atomicAdd(&cursors[e], 1);
        entry_token[pos] = t;
        entry_w[pos] = topk_w[t * 2 + k];
    }
}

// ---------------- GEMM1 (W2 transpose at head — r5/r6 config, best measured) ----------------
// Bids [0,4096): W2-T (rt-fastest); transposes drain as a mostly-serial prologue
// with only boundary mixing into the GEMM (full interleave regressed — r9: L2
// pollution, +93MB FETCH). Bids >= 4096: 128x128 GEMM, BK=32, XOR swizzle, dbuf
// LDS, XCD-aware bijective swizzle (4096 % 8 == 0 preserves bid%8 -> XCD).

union __align__(16) G1Smem {
    struct { unsigned short As[2][4096]; unsigned short Bs[2][4096]; int toks[128]; } g;
    float tile[128 * 68];   // 34 KB
};

__global__ __launch_bounds__(256, 3) void gemm1_kernel(
    const unsigned short* __restrict__ xb,    // [N_TOK][DIM] bf16
    const unsigned short* __restrict__ w1t,   // [E][FFN][DIM] bf16
    const float* __restrict__ b1,             // [E][FFN]
    const int* __restrict__ offs,
    const int* __restrict__ entry_token,
    unsigned short* __restrict__ h,           // [NENT+128][FFN] bf16
    const float* __restrict__ W2,             // [E][FFN][DIM] f32
    unsigned short* __restrict__ w2t)         // [E][DIM][FFN] bf16
{
    __shared__ G1Smem sm;
    int bid0 = blockIdx.x;
    if (bid0 < 4096) {
        // W2: R=FFN=4096 (32 rt), C=DIM=1024 (16 ct)
        int rt = bid0 & 31;
        int ct = (bid0 >> 5) & 15;
        int e  = bid0 >> 9;
        transpose_tile(W2 + (size_t)e * DIM * FFN, w2t + (size_t)e * DIM * FFN,
                       FFN, DIM, rt * 128, ct * 64, sm.tile);
        return;
    }

    int bid   = bid0 - 4096;
    int xcd   = bid & 7;
    int inner = bid >> 3;
    int gq    = inner / MAXM;             // 0..31
    int mt    = inner - gq * MAXM;
    int g     = gq * 8 + xcd;             // group 0..255
    int e     = g >> 5;
    int nt    = g & 31;
    int base = offs[e];
    int cnt  = offs[e + 1] - base;
    int m0   = mt * 128;
    if (m0 >= cnt) return;
    int f0   = nt * 128;

    auto& As   = sm.g.As;
    auto& Bs   = sm.g.Bs;
    auto& toks = sm.g.toks;

    int tid = threadIdx.x;
    if (tid < 128) {
        int r = m0 + tid;
        toks[tid] = entry_token[base + (r < cnt ? r : 0)];
    }
    __syncthreads();

    int wave = tid >> 6, lane = tid & 63;
    int wm = (wave >> 1) * 64, wn = (wave & 1) * 64;

    int lr = lane >> 2, sl = lane & 3;
    int g0 = (sl ^ ((lr >> 1) & 3)) * 8;
    const unsigned short* aG[2];
    const unsigned short* bG[2];
    int ldsOff[2];
#pragma unroll
    for (int c = 0; c < 2; c++) {
        int row = wave * 32 + c * 16 + lr;
        aG[c] = xb + (size_t)toks[row] * DIM + g0;
        bG[c] = w1t + ((size_t)e * FFN + f0 + row) * DIM + g0;
        ldsOff[c] = (wave * 32 + c * 16) * 32;
    }

    floatx4 acc[4][4];
#pragma unroll
    for (int i = 0; i < 4; i++)
#pragma unroll
        for (int j = 0; j < 4; j++) acc[i][j] = (floatx4)0.f;

    int quad = lane >> 4, rm = lane & 15;
    int slf  = (quad ^ ((rm >> 1) & 3)) * 8;
    int arow = (wm + rm) * 32;
    int brow = (wn + rm) * 32;

#pragma unroll
    for (int c = 0; c < 2; c++) {
        GLOAD_LDS16(aG[c], &As[0][ldsOff[c]]);
        GLOAD_LDS16(bG[c], &Bs[0][ldsOff[c]]);
        aG[c] += 32; bG[c] += 32;
    }

    int cur = 0;
    for (int kk = 0; kk < DIM / 32; kk++) {
        __syncthreads();
        short8 af[4], bfr[4];
#pragma unroll
        for (int mi = 0; mi < 4; mi++) af[mi] = *(const short8*)&As[cur][arow + mi * 512 + slf];
#pragma unroll
        for (int ni = 0; ni < 4; ni++) bfr[ni] = *(const short8*)&Bs[cur][brow + ni * 512 + slf];
        if (kk + 1 < DIM / 32) {
            int nxt = cur ^ 1;
#pragma unroll
            for (int c = 0; c < 2; c++) {
                GLOAD_LDS16(aG[c], &As[nxt][ldsOff[c]]);
                GLOAD_LDS16(bG[c], &Bs[nxt][ldsOff[c]]);
                aG[c] += 32; bG[c] += 32;
            }
        }
#pragma unroll
        for (int mi = 0; mi < 4; mi++)
#pragma unroll
            for (int ni = 0; ni < 4; ni++)
                acc[mi][ni] = __builtin_amdgcn_mfma_f32_16x16x32_bf16(af[mi], bfr[ni], acc[mi][ni], 0, 0, 0);
        cur ^= 1;
    }

#pragma unroll
    for (int mi = 0; mi < 4; mi++) {
        int mbase = wm + mi * 16 + quad * 4;
#pragma unroll
        for (int ni = 0; ni < 4; ni++) {
            int f = f0 + wn + ni * 16 + rm;
            float bias = b1[e * FFN + f];
            floatx4 v = acc[mi][ni];
#pragma unroll
            for (int r = 0; r < 4; r++) {
                int row = m0 + mbase + r;
                if (row < cnt) {
                    float t = v[r] + bias;
                    t = t > 0.f ? t : 0.f;
                    h[(size_t)(base + row) * FFN + f] = f2bf(t);
                }
            }
        }
    }
}

// ---------------- GEMM2 + fused combine: y[tok] += w * (h @ W2_e + b2_e) ----------------

__global__ __launch_bounds__(256, 3) void gemm2_kernel(
    const unsigned short* __restrict__ h,     // [NENT+128][FFN]
    const unsigned short* __restrict__ w2t,   // [E][DIM][FFN]
    const float* __restrict__ b2,             // [E][DIM]
    const int* __restrict__ offs,
    const int* __restrict__ entry_token,
    const float* __restrict__ entry_w,
    float* __restrict__ y)                    // [N_TOK][DIM] f32 (pre-zeroed)
{
    int bid  = blockIdx.x;
    int e    = bid & 7;
    int grp  = bid % (8 * MAXM);
    int mt   = grp >> 3;               // m fast
    int nt   = bid / (8 * MAXM);       // 0..7 outer
    int base = offs[e];
    int cnt  = offs[e + 1] - base;
    int m0   = mt * 128;
    if (m0 >= cnt) return;
    int n0   = nt * 128;

    __shared__ unsigned short As[2][128 * 32];
    __shared__ unsigned short Bs[2][128 * 32];

    int tid = threadIdx.x;
    int wave = tid >> 6, lane = tid & 63;
    int wm = (wave >> 1) * 64, wn = (wave & 1) * 64;

    int lr = lane >> 2, sl = lane & 3;
    int g0 = (sl ^ ((lr >> 1) & 3)) * 8;
    const unsigned short* aG[2];
    const unsigned short* bG[2];
    int ldsOff[2];
#pragma unroll
    for (int c = 0; c < 2; c++) {
        int row = wave * 32 + c * 16 + lr;
        aG[c] = h + (size_t)(base + m0 + row) * FFN + g0;
        bG[c] = w2t + ((size_t)e * DIM + n0 + row) * FFN + g0;
        ldsOff[c] = (wave * 32 + c * 16) * 32;
    }

    floatx4 acc[4][4];
#pragma unroll
    for (int i = 0; i < 4; i++)
#pragma unroll
        for (int j = 0; j < 4; j++) acc[i][j] = (floatx4)0.f;

    int quad = lane >> 4, rm = lane & 15;
    int slf  = (quad ^ ((rm >> 1) & 3)) * 8;
    int arow = (wm + rm) * 32;
    int brow = (wn + rm) * 32;

#pragma unroll
    for (int c = 0; c < 2; c++) {
        GLOAD_LDS16(aG[c], &As[0][ldsOff[c]]);
        GLOAD_LDS16(bG[c], &Bs[0][ldsOff[c]]);
        aG[c] += 32; bG[c] += 32;
    }

    int cur = 0;
    for (int kk = 0; kk < FFN / 32; kk++) {
        __syncthreads();
        short8 af[4], bfr[4];
#pragma unroll
        for (int mi = 0; mi < 4; mi++) af[mi] = *(const short8*)&As[cur][arow + mi * 512 + slf];
#pragma unroll
        for (int ni = 0; ni < 4; ni++) bfr[ni] = *(const short8*)&Bs[cur][brow + ni * 512 + slf];
        if (kk + 1 < FFN / 32) {
            int nxt = cur ^ 1;
#pragma unroll
            for (int c = 0; c < 2; c++) {
                GLOAD_LDS16(aG[c], &As[nxt][ldsOff[c]]);
                GLOAD_LDS16(bG[c], &Bs[nxt][ldsOff[c]]);
                aG[c] += 32; bG[c] += 32;
            }
        }
#pragma unroll
        for (int mi = 0; mi < 4; mi++)
#pragma unroll
            for (int ni = 0; ni < 4; ni++)
                acc[mi][ni] = __builtin_amdgcn_mfma_f32_16x16x32_bf16(af[mi], bfr[ni], acc[mi][ni], 0, 0, 0);
        cur ^= 1;
    }

    float bs[4];
#pragma unroll
    for (int ni = 0; ni < 4; ni++) bs[ni] = b2[e * DIM + n0 + wn + ni * 16 + rm];
#pragma unroll
    for (int mi = 0; mi < 4; mi++) {
        int mbase = wm + mi * 16 + quad * 4;
#pragma unroll
        for (int r = 0; r < 4; r++) {
            int row = m0 + mbase + r;
            if (row < cnt) {
                int tok = entry_token[base + row];
                float w = entry_w[base + row];
                float* yr = y + (size_t)tok * DIM;
#pragma unroll
                for (int ni = 0; ni < 4; ni++) {
                    int n = n0 + wn + ni * 16 + rm;
                    atomicAdd(&yr[n], w * (acc[mi][ni][r] + bs[ni]));
                }
            }
        }
    }
}

// ---------------- launch ----------------

extern "C" void kernel_launch(void* const* d_in, const int* in_sizes, int n_in,
                              void* d_out, int out_size, void* d_ws, size_t ws_size,
                              hipStream_t stream) {
    const float* x  = (const float*)d_in[0];
    const float* Wg = (const float*)d_in[1];
    const float* W1 = (const float*)d_in[2];
    const float* b1 = (const float*)d_in[3];
    const float* W2 = (const float*)d_in[4];
    const float* b2 = (const float*)d_in[5];
    float* y = (float*)d_out;

    char* p = (char*)d_ws;
    unsigned short* xb  = (unsigned short*)p; p += (size_t)N_TOK * DIM * 2;          // 16 MB
    unsigned short* w1t = (unsigned short*)p; p += (size_t)NEXP * DIM * FFN * 2;     // 64 MB
    unsigned short* w2t = (unsigned short*)p; p += (size_t)NEXP * DIM * FFN * 2;     // 64 MB
    unsigned short* h   = (unsigned short*)p; p += (size_t)(NENT + 128) * FFN * 2;   // 129 MB
    int*   topk_e      = (int*)p;   p += (size_t)N_TOK * TOPK * 4;
    float* topk_w      = (float*)p; p += (size_t)N_TOK * TOPK * 4;
    int*   entry_token = (int*)p;   p += (size_t)NENT * 4;
    float* entry_w     = (float*)p; p += (size_t)NENT * 4;
    int*   counts      = (int*)p;   p += NEXP * 4;
    int*   cursors     = (int*)p;   p += NEXP * 4;
    int*   offs        = (int*)p;   p += (NEXP + 1) * 4;

    hipMemsetAsync(counts, 0, NEXP * 4 * 2, stream);            // counts + cursors

    prep_kernel<<<4096 + N_TOK / 4, 256, 0, stream>>>(W1, w1t, x, Wg, xb,
                                                      topk_e, topk_w, counts);
    scatter_kernel<<<32 + 512, 256, 0, stream>>>(topk_e, topk_w, counts, offs,
                                                 cursors, entry_token, entry_w, y);
    gemm1_kernel<<<4096 + NEXP * MAXM * (FFN / 128), 256, 0, stream>>>(
        xb, w1t, b1, offs, entry_token, h, W2, w2t);
    gemm2_kernel<<<NEXP * MAXM * (DIM / 128), 256, 0, stream>>>(h, w2t, b2, offs,
                                                                entry_token, entry_w, y);
}

// Round 16
// 989.454 us; speedup vs baseline: 1.5549x; 1.0006x over previous
//
#include <hip/hip_runtime.h>

#define N_TOK 8192
#define DIM   1024
#define FFN   4096
#define NEXP  8
#define TOPK  2
#define NENT  (N_TOK * TOPK)   // 16384
#define MAXM  20               // max 128-row m-tiles per expert

using short8   = __attribute__((ext_vector_type(8))) short;
using ushort8v = __attribute__((ext_vector_type(8))) unsigned short;
using floatx4  = __attribute__((ext_vector_type(4))) float;

__device__ __forceinline__ unsigned short f2bf(float f) {
    union { float f; unsigned u; } v; v.f = f;
    unsigned r = v.u + 0x7fffu + ((v.u >> 16) & 1u);   // round-to-nearest-even
    return (unsigned short)(r >> 16);
}

#define GLOAD_LDS16(gptr, lptr) __builtin_amdgcn_global_load_lds( \
    (__attribute__((address_space(1))) void*)(void*)(gptr),       \
    (__attribute__((address_space(3))) void*)(lptr), 16, 0, 0)

// ---------------- f32->bf16 transpose tile: 128 rows x 64 cols ----------------

__device__ __forceinline__ void transpose_tile(const float* __restrict__ inp,
                                               unsigned short* __restrict__ outp,
                                               int R, int C, int r0, int c0,
                                               float* __restrict__ tile) {
    int t = threadIdx.x;
    int p = t & 15, q = t >> 4;       // col-chunk, row subgroup
#pragma unroll
    for (int i = 0; i < 8; i++) {
        int r = i * 16 + q;
        float4 v = *(const float4*)&inp[(size_t)(r0 + r) * C + c0 + p * 4];
        *(float4*)&tile[r * 68 + p * 4] = v;
    }
    __syncthreads();
    int c = t >> 2, s = t & 3;        // out-row (input col), segment
    unsigned short* orow = outp + (size_t)(c0 + c) * R + r0;
#pragma unroll
    for (int j = 0; j < 4; j++) {
        int rb = j * 32 + s * 8;      // 4-lane groups cover 64 B contiguous
        ushort8v us;
#pragma unroll
        for (int k = 0; k < 8; k++)
            us[k] = f2bf(tile[(rb + k) * 68 + c]);
        *(ushort8v*)&orow[rb] = us;
    }
}

// ---------------- prep: W1 transpose (blocks 0..4095, rt-fastest) + gating ----------------

__global__ __launch_bounds__(256) void prep_kernel(
    const float* __restrict__ W1, unsigned short* __restrict__ w1t,
    const float* __restrict__ x, const float* __restrict__ wg,
    unsigned short* __restrict__ xb,
    int* __restrict__ topk_e, float* __restrict__ topk_w,
    int* __restrict__ counts)
{
    __shared__ float tile[128 * 68];   // 34 KB
    int bid = blockIdx.x;
    if (bid < 4096) {
        // W1: R=DIM=1024 (8 rt), C=FFN=4096 (64 ct)
        int rt = bid & 7;
        int ct = (bid >> 3) & 63;
        int e  = bid >> 9;
        transpose_tile(W1 + (size_t)e * DIM * FFN, w1t + (size_t)e * DIM * FFN,
                       DIM, FFN, rt * 128, ct * 64, tile);
        return;
    }

    // ---- gating (+ x -> bf16), 4 tokens/block ----
    int tid = threadIdx.x;
    int wave = tid >> 6, lane = tid & 63;
    int t = (bid - 4096) * 4 + wave;
    const float* xr = x + (size_t)t * DIM;
    unsigned short* xbr = xb + (size_t)t * DIM;
    float acc[NEXP];
#pragma unroll
    for (int e = 0; e < NEXP; e++) acc[e] = 0.f;
    for (int it = 0; it < DIM / 256; it++) {
        int d = it * 256 + lane * 4;
        float4 xv = *(const float4*)&xr[d];
        ushort4 ub;
        ub.x = f2bf(xv.x); ub.y = f2bf(xv.y); ub.z = f2bf(xv.z); ub.w = f2bf(xv.w);
        *(ushort4*)&xbr[d] = ub;
        const float* wp = wg + (size_t)d * NEXP;
#pragma unroll
        for (int j = 0; j < 4; j++) {
            float xj = (j == 0) ? xv.x : (j == 1) ? xv.y : (j == 2) ? xv.z : xv.w;
            const float4* wr = (const float4*)(wp + j * NEXP);
            float4 w0 = wr[0], w1 = wr[1];
            acc[0] += xj * w0.x; acc[1] += xj * w0.y; acc[2] += xj * w0.z; acc[3] += xj * w0.w;
            acc[4] += xj * w1.x; acc[5] += xj * w1.y; acc[6] += xj * w1.z; acc[7] += xj * w1.w;
        }
    }
#pragma unroll
    for (int e = 0; e < NEXP; e++) {
#pragma unroll
        for (int off = 32; off > 0; off >>= 1) acc[e] += __shfl_xor(acc[e], off);
    }
    if (lane == 0) {
        int e1 = 0; float l1 = acc[0];
        for (int e = 1; e < NEXP; e++) if (acc[e] > l1) { l1 = acc[e]; e1 = e; }
        int e2 = -1; float l2 = -3.4e38f;
        for (int e = 0; e < NEXP; e++) if (e != e1 && acc[e] > l2) { l2 = acc[e]; e2 = e; }
        float w1v = 1.f / (1.f + expf(l2 - l1));   // softmax top-2 renormalized
        topk_e[t * 2]     = e1;  topk_e[t * 2 + 1] = e2;
        topk_w[t * 2]     = w1v; topk_w[t * 2 + 1] = 1.f - w1v;
        atomicAdd(&counts[e1], 1);
        atomicAdd(&counts[e2], 1);
    }
}

// ---------------- scatter (prefix fused) + y zeroing ----------------

__global__ __launch_bounds__(256) void scatter_kernel(const int* __restrict__ topk_e,
                                                      const float* __restrict__ topk_w,
                                                      const int* __restrict__ counts,
                                                      int* __restrict__ offs,
                                                      int* __restrict__ cursors,
                                                      int* __restrict__ entry_token,
                                                      float* __restrict__ entry_w,
                                                      float* __restrict__ y) {
    if (blockIdx.x >= 32) {
        float4 z = make_float4(0.f, 0.f, 0.f, 0.f);
        float4* yp = (float4*)y;
        size_t base = (size_t)(blockIdx.x - 32) * 256 + threadIdx.x;
#pragma unroll
        for (int i = 0; i < 16; i++)
            yp[base + (size_t)i * 512 * 256] = z;
        return;
    }
    int off_[NEXP]; int s = 0;
#pragma unroll
    for (int e = 0; e < NEXP; e++) { off_[e] = s; s += counts[e]; }
    if (blockIdx.x == 0 && threadIdx.x == 0) {
#pragma unroll
        for (int e = 0; e < NEXP; e++) offs[e] = off_[e];
        offs[NEXP] = s;
    }
    int t = blockIdx.x * 256 + threadIdx.x;
#pragma unroll
    for (int k = 0; k < TOPK; k++) {
        int e = topk_e[t * 2 + k];
        int pos = off_[e] + atomicAdd(&cursors[e], 1);
        entry_token[pos] = t;
        entry_w[pos] = topk_w[t * 2 + k];
    }
}

// ---------------- GEMM1 (W2 transpose at head) ----------------
// launch_bounds(256,4): VGPR=56 is nowhere near the cap; LDS 34.8KB x 4 =
// 139KB <= 160KB -> 4 blocks/CU (was 3). The 2-barrier structure's stall is
// the all-wave vmcnt(0) drain at s_barrier; a 4th independent block computes
// through another block's drain (m114 cross-block overlap mechanism).

union __align__(16) G1Smem {
    struct { unsigned short As[2][4096]; unsigned short Bs[2][4096]; int toks[128]; } g;
    float tile[128 * 68];   // 34 KB
};

__global__ __launch_bounds__(256, 4) void gemm1_kernel(
    const unsigned short* __restrict__ xb,    // [N_TOK][DIM] bf16
    const unsigned short* __restrict__ w1t,   // [E][FFN][DIM] bf16
    const float* __restrict__ b1,             // [E][FFN]
    const int* __restrict__ offs,
    const int* __restrict__ entry_token,
    unsigned short* __restrict__ h,           // [NENT+128][FFN] bf16
    const float* __restrict__ W2,             // [E][FFN][DIM] f32
    unsigned short* __restrict__ w2t)         // [E][DIM][FFN] bf16
{
    __shared__ G1Smem sm;
    int bid0 = blockIdx.x;
    if (bid0 < 4096) {
        // W2: R=FFN=4096 (32 rt), C=DIM=1024 (16 ct)
        int rt = bid0 & 31;
        int ct = (bid0 >> 5) & 15;
        int e  = bid0 >> 9;
        transpose_tile(W2 + (size_t)e * DIM * FFN, w2t + (size_t)e * DIM * FFN,
                       FFN, DIM, rt * 128, ct * 64, sm.tile);
        return;
    }

    int bid   = bid0 - 4096;
    int xcd   = bid & 7;
    int inner = bid >> 3;
    int gq    = inner / MAXM;             // 0..31
    int mt    = inner - gq * MAXM;
    int g     = gq * 8 + xcd;             // group 0..255
    int e     = g >> 5;
    int nt    = g & 31;
    int base = offs[e];
    int cnt  = offs[e + 1] - base;
    int m0   = mt * 128;
    if (m0 >= cnt) return;
    int f0   = nt * 128;

    auto& As   = sm.g.As;
    auto& Bs   = sm.g.Bs;
    auto& toks = sm.g.toks;

    int tid = threadIdx.x;
    if (tid < 128) {
        int r = m0 + tid;
        toks[tid] = entry_token[base + (r < cnt ? r : 0)];
    }
    __syncthreads();

    int wave = tid >> 6, lane = tid & 63;
    int wm = (wave >> 1) * 64, wn = (wave & 1) * 64;

    int lr = lane >> 2, sl = lane & 3;
    int g0 = (sl ^ ((lr >> 1) & 3)) * 8;
    const unsigned short* aG[2];
    const unsigned short* bG[2];
    int ldsOff[2];
#pragma unroll
    for (int c = 0; c < 2; c++) {
        int row = wave * 32 + c * 16 + lr;
        aG[c] = xb + (size_t)toks[row] * DIM + g0;
        bG[c] = w1t + ((size_t)e * FFN + f0 + row) * DIM + g0;
        ldsOff[c] = (wave * 32 + c * 16) * 32;
    }

    floatx4 acc[4][4];
#pragma unroll
    for (int i = 0; i < 4; i++)
#pragma unroll
        for (int j = 0; j < 4; j++) acc[i][j] = (floatx4)0.f;

    int quad = lane >> 4, rm = lane & 15;
    int slf  = (quad ^ ((rm >> 1) & 3)) * 8;
    int arow = (wm + rm) * 32;
    int brow = (wn + rm) * 32;

#pragma unroll
    for (int c = 0; c < 2; c++) {
        GLOAD_LDS16(aG[c], &As[0][ldsOff[c]]);
        GLOAD_LDS16(bG[c], &Bs[0][ldsOff[c]]);
        aG[c] += 32; bG[c] += 32;
    }

    int cur = 0;
    for (int kk = 0; kk < DIM / 32; kk++) {
        __syncthreads();
        short8 af[4], bfr[4];
#pragma unroll
        for (int mi = 0; mi < 4; mi++) af[mi] = *(const short8*)&As[cur][arow + mi * 512 + slf];
#pragma unroll
        for (int ni = 0; ni < 4; ni++) bfr[ni] = *(const short8*)&Bs[cur][brow + ni * 512 + slf];
        if (kk + 1 < DIM / 32) {
            int nxt = cur ^ 1;
#pragma unroll
            for (int c = 0; c < 2; c++) {
                GLOAD_LDS16(aG[c], &As[nxt][ldsOff[c]]);
                GLOAD_LDS16(bG[c], &Bs[nxt][ldsOff[c]]);
                aG[c] += 32; bG[c] += 32;
            }
        }
#pragma unroll
        for (int mi = 0; mi < 4; mi++)
#pragma unroll
            for (int ni = 0; ni < 4; ni++)
                acc[mi][ni] = __builtin_amdgcn_mfma_f32_16x16x32_bf16(af[mi], bfr[ni], acc[mi][ni], 0, 0, 0);
        cur ^= 1;
    }

#pragma unroll
    for (int mi = 0; mi < 4; mi++) {
        int mbase = wm + mi * 16 + quad * 4;
#pragma unroll
        for (int ni = 0; ni < 4; ni++) {
            int f = f0 + wn + ni * 16 + rm;
            float bias = b1[e * FFN + f];
            floatx4 v = acc[mi][ni];
#pragma unroll
            for (int r = 0; r < 4; r++) {
                int row = m0 + mbase + r;
                if (row < cnt) {
                    float t = v[r] + bias;
                    t = t > 0.f ? t : 0.f;
                    h[(size_t)(base + row) * FFN + f] = f2bf(t);
                }
            }
        }
    }
}

// ---------------- GEMM2 + fused combine: y[tok] += w * (h @ W2_e + b2_e) ----------------
// launch_bounds(256,4): LDS 32KB x 4 = 128KB <= 160KB -> 4 blocks/CU.

__global__ __launch_bounds__(256, 4) void gemm2_kernel(
    const unsigned short* __restrict__ h,     // [NENT+128][FFN]
    const unsigned short* __restrict__ w2t,   // [E][DIM][FFN]
    const float* __restrict__ b2,             // [E][DIM]
    const int* __restrict__ offs,
    const int* __restrict__ entry_token,
    const float* __restrict__ entry_w,
    float* __restrict__ y)                    // [N_TOK][DIM] f32 (pre-zeroed)
{
    int bid  = blockIdx.x;
    int e    = bid & 7;
    int grp  = bid % (8 * MAXM);
    int mt   = grp >> 3;               // m fast
    int nt   = bid / (8 * MAXM);       // 0..7 outer
    int base = offs[e];
    int cnt  = offs[e + 1] - base;
    int m0   = mt * 128;
    if (m0 >= cnt) return;
    int n0   = nt * 128;

    __shared__ unsigned short As[2][128 * 32];
    __shared__ unsigned short Bs[2][128 * 32];

    int tid = threadIdx.x;
    int wave = tid >> 6, lane = tid & 63;
    int wm = (wave >> 1) * 64, wn = (wave & 1) * 64;

    int lr = lane >> 2, sl = lane & 3;
    int g0 = (sl ^ ((lr >> 1) & 3)) * 8;
    const unsigned short* aG[2];
    const unsigned short* bG[2];
    int ldsOff[2];
#pragma unroll
    for (int c = 0; c < 2; c++) {
        int row = wave * 32 + c * 16 + lr;
        aG[c] = h + (size_t)(base + m0 + row) * FFN + g0;
        bG[c] = w2t + ((size_t)e * DIM + n0 + row) * FFN + g0;
        ldsOff[c] = (wave * 32 + c * 16) * 32;
    }

    floatx4 acc[4][4];
#pragma unroll
    for (int i = 0; i < 4; i++)
#pragma unroll
        for (int j = 0; j < 4; j++) acc[i][j] = (floatx4)0.f;

    int quad = lane >> 4, rm = lane & 15;
    int slf  = (quad ^ ((rm >> 1) & 3)) * 8;
    int arow = (wm + rm) * 32;
    int brow = (wn + rm) * 32;

#pragma unroll
    for (int c = 0; c < 2; c++) {
        GLOAD_LDS16(aG[c], &As[0][ldsOff[c]]);
        GLOAD_LDS16(bG[c], &Bs[0][ldsOff[c]]);
        aG[c] += 32; bG[c] += 32;
    }

    int cur = 0;
    for (int kk = 0; kk < FFN / 32; kk++) {
        __syncthreads();
        short8 af[4], bfr[4];
#pragma unroll
        for (int mi = 0; mi < 4; mi++) af[mi] = *(const short8*)&As[cur][arow + mi * 512 + slf];
#pragma unroll
        for (int ni = 0; ni < 4; ni++) bfr[ni] = *(const short8*)&Bs[cur][brow + ni * 512 + slf];
        if (kk + 1 < FFN / 32) {
            int nxt = cur ^ 1;
#pragma unroll
            for (int c = 0; c < 2; c++) {
                GLOAD_LDS16(aG[c], &As[nxt][ldsOff[c]]);
                GLOAD_LDS16(bG[c], &Bs[nxt][ldsOff[c]]);
                aG[c] += 32; bG[c] += 32;
            }
        }
#pragma unroll
        for (int mi = 0; mi < 4; mi++)
#pragma unroll
            for (int ni = 0; ni < 4; ni++)
                acc[mi][ni] = __builtin_amdgcn_mfma_f32_16x16x32_bf16(af[mi], bfr[ni], acc[mi][ni], 0, 0, 0);
        cur ^= 1;
    }

    float bs[4];
#pragma unroll
    for (int ni = 0; ni < 4; ni++) bs[ni] = b2[e * DIM + n0 + wn + ni * 16 + rm];
#pragma unroll
    for (int mi = 0; mi < 4; mi++) {
        int mbase = wm + mi * 16 + quad * 4;
#pragma unroll
        for (int r = 0; r < 4; r++) {
            int row = m0 + mbase + r;
            if (row < cnt) {
                int tok = entry_token[base + row];
                float w = entry_w[base + row];
                float* yr = y + (size_t)tok * DIM;
#pragma unroll
                for (int ni = 0; ni < 4; ni++) {
                    int n = n0 + wn + ni * 16 + rm;
                    atomicAdd(&yr[n], w * (acc[mi][ni][r] + bs[ni]));
                }
            }
        }
    }
}

// ---------------- launch ----------------

extern "C" void kernel_launch(void* const* d_in, const int* in_sizes, int n_in,
                              void* d_out, int out_size, void* d_ws, size_t ws_size,
                              hipStream_t stream) {
    const float* x  = (const float*)d_in[0];
    const float* Wg = (const float*)d_in[1];
    const float* W1 = (const float*)d_in[2];
    const float* b1 = (const float*)d_in[3];
    const float* W2 = (const float*)d_in[4];
    const float* b2 = (const float*)d_in[5];
    float* y = (float*)d_out;

    char* p = (char*)d_ws;
    unsigned short* xb  = (unsigned short*)p; p += (size_t)N_TOK * DIM * 2;          // 16 MB
    unsigned short* w1t = (unsigned short*)p; p += (size_t)NEXP * DIM * FFN * 2;     // 64 MB
    unsigned short* w2t = (unsigned short*)p; p += (size_t)NEXP * DIM * FFN * 2;     // 64 MB
    unsigned short* h   = (unsigned short*)p; p += (size_t)(NENT + 128) * FFN * 2;   // 129 MB
    int*   topk_e      = (int*)p;   p += (size_t)N_TOK * TOPK * 4;
    float* topk_w      = (float*)p; p += (size_t)N_TOK * TOPK * 4;
    int*   entry_token = (int*)p;   p += (size_t)NENT * 4;
    float* entry_w     = (float*)p; p += (size_t)NENT * 4;
    int*   counts      = (int*)p;   p += NEXP * 4;
    int*   cursors     = (int*)p;   p += NEXP * 4;
    int*   offs        = (int*)p;   p += (NEXP + 1) * 4;

    hipMemsetAsync(counts, 0, NEXP * 4 * 2, stream);            // counts + cursors

    prep_kernel<<<4096 + N_TOK / 4, 256, 0, stream>>>(W1, w1t, x, Wg, xb,
                                                      topk_e, topk_w, counts);
    scatter_kernel<<<32 + 512, 256, 0, stream>>>(topk_e, topk_w, counts, offs,
                                                 cursors, entry_token, entry_w, y);
    gemm1_kernel<<<4096 + NEXP * MAXM * (FFN / 128), 256, 0, stream>>>(
        xb, w1t, b1, offs, entry_token, h, W2, w2t);
    gemm2_kernel<<<NEXP * MAXM * (DIM / 128), 256, 0, stream>>>(h, w2t, b2, offs,
                                                                entry_token, entry_w, y);
}